// Round 2
// baseline (202.904 us; speedup 1.0000x reference)
//
#include <hip/hip_runtime.h>

typedef __attribute__((ext_vector_type(8))) __bf16 bf16x8;
typedef __attribute__((ext_vector_type(2))) __bf16 bf16x2;
typedef __attribute__((ext_vector_type(4))) float f32x4;

#define LOG2E 1.44269504088896f
#define KSWZ(t) (((t) & 7) << 4)
#define VSWZ(d) ((((d) & 7) ^ (((d) >> 3) & 7)) << 4)

// 28 instances of dilated causal attention, each L=2048, d=64.
// q/k/v: (1, 8192, 12, 64) fp32 -> elem = tok*768 + head*64 + d.
// Block = 512 threads (8 waves): waves 0-3 = KV-group 0 (even kt),
// waves 4-7 = KV-group 1 (odd kt), same 64 q-rows. Merge partials at end.
// LDS pool (48 KB): [0,16K) K0|V0  [16K,32K) K1|V1  [32K,48K) P[8 waves].
// Merge overlay: acc -> [0,16K), m/l -> P[4..7].

__global__ __launch_bounds__(512, 6)
void dilattn_kernel(const float* __restrict__ Qg, const float* __restrict__ Kg,
                    const float* __restrict__ Vg, float* __restrict__ Og,
                    const int* __restrict__ causal_p)
{
    extern __shared__ char pool[];

    const int bid  = blockIdx.x;
    const int inst = bid % 28;
    const int qt   = 31 - (bid / 28);          // heavy (long) tiles dispatch first
    int head, sstart, r, off;
    if (inst < 16)      { head = inst & 3;          sstart = (inst >> 2) * 2048; r = 1; off = 0; }
    else if (inst < 24) { int j = inst - 16; head = 4 + (j & 3); sstart = (j >> 2) * 4096; r = 2; off = 1; }
    else                { head = 8 + (inst - 24);   sstart = 0;                  r = 4; off = 2; }

    const int causal = *causal_p;
    const int tid  = threadIdx.x;
    const int lane = tid & 63;
    const int wave = tid >> 6;                 // 0..7
    const int grp  = wave >> 2;                // 0: even kt, 1: odd kt
    const int wv   = wave & 3;                 // q-row sub-tile
    const int l15  = lane & 15;
    const int lhi  = lane >> 4;
    const int t2   = tid & 255;                // thread id within group

    char* Kb = pool + grp * 16384;             // 8 KB K tile
    char* Vb = Kb + 8192;                      // 8 KB V^T tile
    char* Pb = pool + 32768 + wave * 2048;     // 2 KB per-wave P bridge

    // ---- Q fragments (scale * log2e folded in) ----
    const int qrow_base = qt * 64 + wv * 16;
    const float qscale = 0.125f * LOG2E;
    bf16x8 qfrag[2];
    {
        int qr = qrow_base + l15;
        long qtok = sstart + off + (long)r * qr;
        const float* qp = Qg + qtok * 768 + head * 64 + lhi * 8;
#pragma unroll
        for (int dc = 0; dc < 2; dc++) {
            f32x4 a = *(const f32x4*)(qp + dc * 32);
            f32x4 b = *(const f32x4*)(qp + dc * 32 + 4);
#pragma unroll
            for (int j = 0; j < 4; j++) {
                qfrag[dc][j]     = (__bf16)(a[j] * qscale);
                qfrag[dc][4 + j] = (__bf16)(b[j] * qscale);
            }
        }
    }

    f32x4 acc[4] = {};
    float m_run[4] = {-INFINITY, -INFINITY, -INFINITY, -INFINITY};
    float l_run[4] = {0.f, 0.f, 0.f, 0.f};

    const int nkt = causal ? (qt + 1) : 32;
    const int nIter = (nkt + 1) >> 1;

    for (int i = 0; i < nIter; i++) {
        const int kt = 2 * i + grp;
        const bool active = kt < nkt;
        __syncthreads();                       // prior tile's readers done
        if (active) {
            // ---- K staging: thread = (token, d-quarter) ----
            {
                int tok = t2 >> 2, q4 = t2 & 3, d0k = q4 * 16;
                long ktok = sstart + off + (long)r * (kt * 64 + tok);
                const float* kp = Kg + ktok * 768 + head * 64 + d0k;
                f32x4 k0 = *(const f32x4*)(kp);
                f32x4 k1 = *(const f32x4*)(kp + 4);
                f32x4 k2 = *(const f32x4*)(kp + 8);
                f32x4 k3 = *(const f32x4*)(kp + 12);
                bf16x8 w0, w1;
#pragma unroll
                for (int j = 0; j < 4; j++) {
                    w0[j] = (__bf16)k0[j]; w0[4 + j] = (__bf16)k1[j];
                    w1[j] = (__bf16)k2[j]; w1[4 + j] = (__bf16)k3[j];
                }
                int kbase = tok * 128 + q4 * 32;
                *(bf16x8*)(Kb + ((kbase)      ^ KSWZ(tok))) = w0;
                *(bf16x8*)(Kb + ((kbase + 16) ^ KSWZ(tok))) = w1;
            }
            // ---- V staging (transposed): thread = (token-pair, 8 d) ----
            {
                int tokp = t2 >> 3, d8 = (t2 & 7) * 8;
                long vt0 = sstart + off + (long)r * (kt * 64 + 2 * tokp);
                const float* vp0 = Vg + vt0 * 768 + head * 64 + d8;
                const float* vp1 = vp0 + (long)r * 768;
                f32x4 a0 = *(const f32x4*)(vp0);
                f32x4 a1 = *(const f32x4*)(vp0 + 4);
                f32x4 b0 = *(const f32x4*)(vp1);
                f32x4 b1 = *(const f32x4*)(vp1 + 4);
#pragma unroll
                for (int j = 0; j < 4; j++) {
                    int d = d8 + j;
                    bf16x2 w; w[0] = (__bf16)a0[j]; w[1] = (__bf16)b0[j];
                    *(bf16x2*)(Vb + ((d * 128 + tokp * 4) ^ VSWZ(d))) = w;
                    int d2 = d8 + 4 + j;
                    bf16x2 w2; w2[0] = (__bf16)a1[j]; w2[1] = (__bf16)b1[j];
                    *(bf16x2*)(Vb + ((d2 * 128 + tokp * 4) ^ VSWZ(d2))) = w2;
                }
            }
        }
        __syncthreads();                       // tile staged
        if (active) {
            // ---- S = Q K^T ----
            f32x4 s[4];
#pragma unroll
            for (int nt = 0; nt < 4; nt++) {
                f32x4 c = {};
#pragma unroll
                for (int dc = 0; dc < 2; dc++) {
                    int krow = nt * 16 + l15;
                    const bf16x8 kf = *(const bf16x8*)(Kb +
                        ((krow * 128 + dc * 64 + lhi * 16) ^ KSWZ(krow)));
                    c = __builtin_amdgcn_mfma_f32_16x16x32_bf16(qfrag[dc], kf, c, 0, 0, 0);
                }
                s[nt] = c;
            }
            // ---- causal mask (diagonal tile only) ----
            if (causal && kt == qt) {
#pragma unroll
                for (int nt = 0; nt < 4; nt++) {
                    int kc = kt * 64 + nt * 16 + l15;
#pragma unroll
                    for (int reg = 0; reg < 4; reg++) {
                        int qr = qrow_base + lhi * 4 + reg;
                        if (kc > qr) s[nt][reg] = -INFINITY;
                    }
                }
            }
            // ---- online softmax ----
            float sc_reg[4];
#pragma unroll
            for (int reg = 0; reg < 4; reg++) {
                float mt = fmaxf(fmaxf(s[0][reg], s[1][reg]), fmaxf(s[2][reg], s[3][reg]));
#pragma unroll
                for (int x = 1; x < 16; x <<= 1) mt = fmaxf(mt, __shfl_xor(mt, x));
                float mn = fmaxf(m_run[reg], mt);
                float sc = exp2f(m_run[reg] - mn);
                float ps = 0.f;
#pragma unroll
                for (int nt = 0; nt < 4; nt++) {
                    float p = exp2f(s[nt][reg] - mn);
                    s[nt][reg] = p;
                    ps += p;
                }
#pragma unroll
                for (int x = 1; x < 16; x <<= 1) ps += __shfl_xor(ps, x);
                l_run[reg] = l_run[reg] * sc + ps;
                m_run[reg] = mn;
                sc_reg[reg] = sc;
            }
#pragma unroll
            for (int dt = 0; dt < 4; dt++)
#pragma unroll
                for (int reg = 0; reg < 4; reg++) acc[dt][reg] *= sc_reg[reg];
            // ---- P -> wave-private LDS bridge ----
#pragma unroll
            for (int reg = 0; reg < 4; reg++) {
                int row = lhi * 4 + reg;
                int rs = (row & 7) << 4;
#pragma unroll
                for (int nt = 0; nt < 4; nt++) {
                    int colb = (nt * 16 + l15) * 2;
                    *(__bf16*)(Pb + ((row * 128 + colb) ^ rs)) = (__bf16)s[nt][reg];
                }
            }
            // ---- O += P V ----
#pragma unroll
            for (int kc = 0; kc < 2; kc++) {
                const bf16x8 pf = *(const bf16x8*)(Pb +
                    ((l15 * 128 + kc * 64 + lhi * 16) ^ ((l15 & 7) << 4)));
#pragma unroll
                for (int dt = 0; dt < 4; dt++) {
                    int drow = dt * 16 + l15;
                    const bf16x8 vf = *(const bf16x8*)(Vb +
                        ((drow * 128 + kc * 64 + lhi * 16) ^ VSWZ(drow)));
                    acc[dt] = __builtin_amdgcn_mfma_f32_16x16x32_bf16(pf, vf, acc[dt], 0, 0, 0);
                }
            }
        }
    }

    // ---- merge group 1 partials into group 0 ----
    __syncthreads();                           // all compute done; K0/V0 free
    if (wave >= 4) {
        float* ab = (float*)(pool + wv * 4096);
#pragma unroll
        for (int dt = 0; dt < 4; dt++)
            *(f32x4*)(ab + lane * 16 + dt * 4) = acc[dt];
        float* ml = (float*)(pool + 32768 + wave * 2048);
        if (l15 == 0) {
#pragma unroll
            for (int reg = 0; reg < 4; reg++) {
                int row = lhi * 4 + reg;
                ml[row * 2]     = m_run[reg];
                ml[row * 2 + 1] = l_run[reg];
            }
        }
    }
    __syncthreads();
    if (wave < 4) {
        float* ab = (float*)(pool + wv * 4096);
        float* ml = (float*)(pool + 32768 + (4 + wv) * 2048);
#pragma unroll
        for (int reg = 0; reg < 4; reg++) {
            int row = lhi * 4 + reg;
            float m1 = ml[row * 2];
            float l1 = ml[row * 2 + 1];
            float m0 = m_run[reg], l0 = l_run[reg];
            float m  = fmaxf(m0, m1);
            float sc0 = exp2f(m0 - m);
            float sc1 = exp2f(m1 - m);
            l_run[reg] = l0 * sc0 + l1 * sc1;
#pragma unroll
            for (int dt = 0; dt < 4; dt++)
                acc[dt][reg] = acc[dt][reg] * sc0 + ab[lane * 16 + dt * 4 + reg] * sc1;
        }
        // ---- epilogue: normalize + scatter ----
#pragma unroll
        for (int reg = 0; reg < 4; reg++) {
            float inv = 1.0f / l_run[reg];
            int qr = qrow_base + lhi * 4 + reg;
            long tok = sstart + off + (long)r * qr;
            float* op = Og + tok * 768 + head * 64 + l15;
#pragma unroll
            for (int dt = 0; dt < 4; dt++) op[dt * 16] = acc[dt][reg] * inv;
        }
    }
}

extern "C" void kernel_launch(void* const* d_in, const int* in_sizes, int n_in,
                              void* d_out, int out_size, void* d_ws, size_t ws_size,
                              hipStream_t stream)
{
    const float* q = (const float*)d_in[0];
    const float* k = (const float*)d_in[1];
    const float* v = (const float*)d_in[2];
    const int* causal = (const int*)d_in[3];
    float* out = (float*)d_out;

    hipMemsetAsync(d_out, 0, (size_t)out_size * sizeof(float), stream);

    dilattn_kernel<<<dim3(28 * 32), dim3(512), 49152, stream>>>(q, k, v, out, causal);
}